// Round 5
// baseline (457.102 us; speedup 1.0000x reference)
//
#include <hip/hip_runtime.h>
#include <math.h>

// Problem constants (B,C,H,W) = (32,256,128,128), downsample 0.5 -> (64,64)
#define NB 32
#define NC 256
#define NH 128
#define NW 128
#define NDH 64
#define NDW 64
#define NHW (NH * NW)          // 16384
#define NCELLS (NDH * NDW)     // 4096
#define OUT0_N (NB * NC * NCELLS)       // out: 33,554,432 floats
#define OUT1_BASE OUT0_N
#define OUT1_N (NB * 2 * NHW)           // offset: 1,048,576 floats
#define OUT2_BASE (OUT1_BASE + OUT1_N)  // destination: 134,217,728 floats

#define EPSF 1e-5f

typedef unsigned short u16;
typedef unsigned int   u32;

// ---- workspace layout (bytes), 16B-aligned by construction ----
#define WS_CELLS   ((size_t)0)                       // u16 [NB*NHW]   1 MB
#define WS_ATTS    (WS_CELLS + (size_t)NB*NHW*2)     // f32 [NB*NHW]   2 MB
#define WS_ECOMB   (WS_ATTS + (size_t)NB*NHW*4)      // u32 [NB*NHW]   2 MB  (cell<<16 | pix)
#define WS_ASUM    (WS_ECOMB + (size_t)NB*NHW*4)     // f32 [NB*NCELLS] 512 KB
#define WS_BASE_NEED (WS_ASUM + (size_t)NB*NCELLS*4) // ~5.5 MB
#define WS_XATT    WS_BASE_NEED                      // bf16 [NB*NC*NHW] 268 MB
#define WS_XATT_NEED (WS_XATT + (size_t)NB*NC*NHW*2)

__device__ __forceinline__ u16 f32_to_bf16_rn(float f) {
    const u32 u = __float_as_uint(f);
    return (u16)((u + 0x7FFFu + ((u >> 16) & 1u)) >> 16);
}

// ============================================================================
// Shared gather inner loop: 64 sorted packed entries per thread, processed as
// FOUR independent run-length streams of 16 (4x ILP on the serial
// cmp->select->add chain). Flushes to LDS acc via atomics (rare: ~1/4 entries).
// ============================================================================
#define BF16V(E) __uint_as_float((u32)xpl[(E) & 0xFFFFu] << 16)
#define ACCUM(CUR, S, E, V)                                                   \
    {                                                                         \
        const int cl_ = (int)((E) >> 16);                                     \
        if (cl_ != (CUR)) { atomicAdd(&acc[(CUR)], (S)); (S) = 0.f; (CUR) = cl_; } \
        (S) += (V);                                                           \
    }

__device__ __forceinline__ void gather_accum(
    const u16* __restrict__ xpl, float* __restrict__ acc,
    const u32* __restrict__ el)
{
    float s0 = 0.f, s1 = 0.f, s2 = 0.f, s3 = 0.f;
    int   c0 = (int)(el[0]  >> 16);
    int   c1 = (int)(el[16] >> 16);
    int   c2 = (int)(el[32] >> 16);
    int   c3 = (int)(el[48] >> 16);

    #pragma unroll
    for (int ch = 0; ch < 4; ++ch) {
        const uint4 e0 = *reinterpret_cast<const uint4*>(el + ch * 4);
        const uint4 e1 = *reinterpret_cast<const uint4*>(el + 16 + ch * 4);
        const uint4 e2 = *reinterpret_cast<const uint4*>(el + 32 + ch * 4);
        const uint4 e3 = *reinterpret_cast<const uint4*>(el + 48 + ch * 4);
        const float v00 = BF16V(e0.x), v01 = BF16V(e0.y), v02 = BF16V(e0.z), v03 = BF16V(e0.w);
        const float v10 = BF16V(e1.x), v11 = BF16V(e1.y), v12 = BF16V(e1.z), v13 = BF16V(e1.w);
        const float v20 = BF16V(e2.x), v21 = BF16V(e2.y), v22 = BF16V(e2.z), v23 = BF16V(e2.w);
        const float v30 = BF16V(e3.x), v31 = BF16V(e3.y), v32 = BF16V(e3.z), v33 = BF16V(e3.w);
        ACCUM(c0, s0, e0.x, v00); ACCUM(c1, s1, e1.x, v10); ACCUM(c2, s2, e2.x, v20); ACCUM(c3, s3, e3.x, v30);
        ACCUM(c0, s0, e0.y, v01); ACCUM(c1, s1, e1.y, v11); ACCUM(c2, s2, e2.y, v21); ACCUM(c3, s3, e3.y, v31);
        ACCUM(c0, s0, e0.z, v02); ACCUM(c1, s1, e1.z, v12); ACCUM(c2, s2, e2.z, v22); ACCUM(c3, s3, e3.z, v32);
        ACCUM(c0, s0, e0.w, v03); ACCUM(c1, s1, e1.w, v13); ACCUM(c2, s2, e2.w, v23); ACCUM(c3, s3, e3.w, v33);
    }
    atomicAdd(&acc[c0], s0);
    atomicAdd(&acc[c1], s1);
    atomicAdd(&acc[c2], s2);
    atomicAdd(&acc[c3], s3);
}

// ============================================================================
// K1a (xatt variant): 1x1 conv (3 outs) -> offset, destination, cells, atts,
// AND bf16(x*att) premultiplied planes into ws. x stays in registers between
// the conv dot and the xatt write, so x is read from HBM exactly once here.
// ============================================================================
__global__ __launch_bounds__(256) void k_conv_x(
    const float* __restrict__ x, const float* __restrict__ cw,
    const float* __restrict__ cb, float* __restrict__ out,
    u16* __restrict__ cells, float* __restrict__ atts, u16* __restrict__ xatt)
{
    __shared__ float cwS[3][NC];
    __shared__ float red[256][13];
    __shared__ float attv[64];
    __shared__ int   cellv[64];

    const int t    = threadIdx.x;
    const int blk  = blockIdx.x;
    const int b    = blk >> 8;
    const int tile = blk & 255;
    const int h    = tile >> 1;
    const int w0   = (tile & 1) << 6;
    const int pixbase = h * NW + w0;

    cwS[0][t] = cw[t];
    cwS[1][t] = cw[NC + t];
    cwS[2][t] = cw[2 * NC + t];
    __syncthreads();

    const int ct = t >> 4;            // channel group 0..15
    const int pg = (t & 15) << 2;     // pixel quad base 0..60
    const float* xb = x + (size_t)b * NC * NHW + pixbase + pg;

    float4 xr[16];
    float p00 = 0, p01 = 0, p02 = 0;
    float p10 = 0, p11 = 0, p12 = 0;
    float p20 = 0, p21 = 0, p22 = 0;
    float p30 = 0, p31 = 0, p32 = 0;

    #pragma unroll
    for (int i = 0; i < 16; ++i) {
        const int c = (i << 4) + ct;
        const float4 xv = *reinterpret_cast<const float4*>(xb + (size_t)c * NHW);
        xr[i] = xv;
        const float wc0 = cwS[0][c], wc1 = cwS[1][c], wc2 = cwS[2][c];
        p00 += xv.x * wc0; p01 += xv.x * wc1; p02 += xv.x * wc2;
        p10 += xv.y * wc0; p11 += xv.y * wc1; p12 += xv.y * wc2;
        p20 += xv.z * wc0; p21 += xv.z * wc1; p22 += xv.z * wc2;
        p30 += xv.w * wc0; p31 += xv.w * wc1; p32 += xv.w * wc2;
    }

    red[t][0]  = p00; red[t][1]  = p01; red[t][2]  = p02;
    red[t][3]  = p10; red[t][4]  = p11; red[t][5]  = p12;
    red[t][6]  = p20; red[t][7]  = p21; red[t][8]  = p22;
    red[t][9]  = p30; red[t][10] = p31; red[t][11] = p32;
    __syncthreads();

    if (t < 64) {
        const int px   = t;
        const int row0 = px >> 2;
        const int col  = (px & 3) * 3;
        float s0 = 0, s1 = 0, s2 = 0;
        #pragma unroll
        for (int j = 0; j < 16; ++j) {
            const int r = row0 + (j << 4);
            s0 += red[r][col];
            s1 += red[r][col + 1];
            s2 += red[r][col + 2];
        }
        const float off0 = s0 + cb[0];
        const float off1 = s1 + cb[1];
        const float att  = expf(s2 + cb[2]);

        const float gy = (float)h * (1.0f / NH);
        const float gx = (float)(w0 + px) * (1.0f / NW);
        const float dyf = fminf(fmaxf(gy + off0, 0.0f), 0.99999f);
        const float dxf = fminf(fmaxf(gx + off1, 0.0f), 0.99999f);
        const int dy = (int)floorf(dyf * (float)NDH);
        const int dx = (int)floorf(dxf * (float)NDW);
        const int cell = dy * NDW + dx;

        cellv[px] = cell;
        attv[px]  = att;
        cells[b * NHW + pixbase + px] = (u16)cell;
        atts [b * NHW + pixbase + px] = att;

        const int o1 = OUT1_BASE + b * 2 * NHW + pixbase + px;
        out[o1]       = off0;
        out[o1 + NHW] = off1;
    }
    __syncthreads();

    const int  c0 = cellv[pg], c1 = cellv[pg + 1], c2 = cellv[pg + 2], c3 = cellv[pg + 3];
    const float a0 = attv[pg], a1 = attv[pg + 1], a2 = attv[pg + 2], a3 = attv[pg + 3];
    float* __restrict__ dst = out + OUT2_BASE;

    #pragma unroll
    for (int i = 0; i < 16; ++i) {
        const int c = (i << 4) + ct;
        const int basec = (b * NC + c) * NCELLS;
        float4 dv;
        dv.x = (float)(basec + c0);
        dv.y = (float)(basec + c1);
        dv.z = (float)(basec + c2);
        dv.w = (float)(basec + c3);
        *reinterpret_cast<float4*>(dst + (size_t)(b * NC + c) * NHW + pixbase + pg) = dv;

        const float4 xv = xr[i];
        const u32 lo = (u32)f32_to_bf16_rn(xv.x * a0)
                     | ((u32)f32_to_bf16_rn(xv.y * a1) << 16);
        const u32 hi = (u32)f32_to_bf16_rn(xv.z * a2)
                     | ((u32)f32_to_bf16_rn(xv.w * a3) << 16);
        *reinterpret_cast<uint2*>(xatt + (size_t)(b * NC + c) * NHW + pixbase + pg)
            = make_uint2(lo, hi);
    }
}

// K1b (no-xatt fallback): round-4 conv.
__global__ __launch_bounds__(256) void k_conv_nx(
    const float* __restrict__ x, const float* __restrict__ cw,
    const float* __restrict__ cb, float* __restrict__ out,
    u16* __restrict__ cells, float* __restrict__ atts)
{
    __shared__ float cwS[3][NC];
    __shared__ float red[256][13];
    __shared__ int   cellv[64];

    const int t    = threadIdx.x;
    const int blk  = blockIdx.x;
    const int b    = blk >> 8;
    const int tile = blk & 255;
    const int h    = tile >> 1;
    const int w0   = (tile & 1) << 6;
    const int pixbase = h * NW + w0;

    cwS[0][t] = cw[t];
    cwS[1][t] = cw[NC + t];
    cwS[2][t] = cw[2 * NC + t];
    __syncthreads();

    const int ct = t >> 4;
    const int pg = (t & 15) << 2;
    const float* xb = x + (size_t)b * NC * NHW + pixbase + pg;

    float p00 = 0, p01 = 0, p02 = 0;
    float p10 = 0, p11 = 0, p12 = 0;
    float p20 = 0, p21 = 0, p22 = 0;
    float p30 = 0, p31 = 0, p32 = 0;

    #pragma unroll
    for (int i = 0; i < 16; ++i) {
        const int c = (i << 4) + ct;
        const float4 xv = *reinterpret_cast<const float4*>(xb + (size_t)c * NHW);
        const float wc0 = cwS[0][c], wc1 = cwS[1][c], wc2 = cwS[2][c];
        p00 += xv.x * wc0; p01 += xv.x * wc1; p02 += xv.x * wc2;
        p10 += xv.y * wc0; p11 += xv.y * wc1; p12 += xv.y * wc2;
        p20 += xv.z * wc0; p21 += xv.z * wc1; p22 += xv.z * wc2;
        p30 += xv.w * wc0; p31 += xv.w * wc1; p32 += xv.w * wc2;
    }

    red[t][0]  = p00; red[t][1]  = p01; red[t][2]  = p02;
    red[t][3]  = p10; red[t][4]  = p11; red[t][5]  = p12;
    red[t][6]  = p20; red[t][7]  = p21; red[t][8]  = p22;
    red[t][9]  = p30; red[t][10] = p31; red[t][11] = p32;
    __syncthreads();

    if (t < 64) {
        const int px   = t;
        const int row0 = px >> 2;
        const int col  = (px & 3) * 3;
        float s0 = 0, s1 = 0, s2 = 0;
        #pragma unroll
        for (int j = 0; j < 16; ++j) {
            const int r = row0 + (j << 4);
            s0 += red[r][col];
            s1 += red[r][col + 1];
            s2 += red[r][col + 2];
        }
        const float off0 = s0 + cb[0];
        const float off1 = s1 + cb[1];
        const float att  = expf(s2 + cb[2]);
        const float gy = (float)h * (1.0f / NH);
        const float gx = (float)(w0 + px) * (1.0f / NW);
        const float dyf = fminf(fmaxf(gy + off0, 0.0f), 0.99999f);
        const float dxf = fminf(fmaxf(gx + off1, 0.0f), 0.99999f);
        const int dy = (int)floorf(dyf * (float)NDH);
        const int dx = (int)floorf(dxf * (float)NDW);
        const int cell = dy * NDW + dx;
        cellv[px] = cell;
        cells[b * NHW + pixbase + px] = (u16)cell;
        atts [b * NHW + pixbase + px] = att;
        const int o1 = OUT1_BASE + b * 2 * NHW + pixbase + px;
        out[o1]       = off0;
        out[o1 + NHW] = off1;
    }
    __syncthreads();

    const int  c0 = cellv[pg], c1 = cellv[pg + 1], c2 = cellv[pg + 2], c3 = cellv[pg + 3];
    float* __restrict__ dst = out + OUT2_BASE;
    #pragma unroll
    for (int i = 0; i < 16; ++i) {
        const int c = (i << 4) + ct;
        const int basec = (b * NC + c) * NCELLS;
        float4 dv;
        dv.x = (float)(basec + c0);
        dv.y = (float)(basec + c1);
        dv.z = (float)(basec + c2);
        dv.w = (float)(basec + c3);
        *reinterpret_cast<float4*>(dst + (size_t)(b * NC + c) * NHW + pixbase + pg) = dv;
    }
}

// ============================================================================
// K2: per-batch counting sort of pixels by cell. One block per b.
// ============================================================================
__global__ __launch_bounds__(1024) void k_sort(
    const u16* __restrict__ cells, const float* __restrict__ atts,
    u32* __restrict__ ecomb, float* __restrict__ asum)
{
    __shared__ u32   hist[NCELLS];
    __shared__ float as_[NCELLS];
    __shared__ u32   ts[1024];

    const int t = threadIdx.x;
    const int b = blockIdx.x;
    const u16*   cb_ = cells + b * NHW;
    const float* ab_ = atts + b * NHW;

    #pragma unroll
    for (int j = 0; j < 4; ++j) { hist[t + 1024 * j] = 0u; as_[t + 1024 * j] = 0.f; }
    __syncthreads();

    #pragma unroll
    for (int j = 0; j < 16; ++j) {
        const int p  = t + 1024 * j;
        const int cl = cb_[p];
        atomicAdd(&hist[cl], 1u);
        atomicAdd(&as_[cl], ab_[p]);
    }
    __syncthreads();

    const u32 h0 = hist[4 * t], h1 = hist[4 * t + 1], h2 = hist[4 * t + 2], h3 = hist[4 * t + 3];
    const u32 T  = h0 + h1 + h2 + h3;
    ts[t] = T;
    __syncthreads();
    for (int off = 1; off < 1024; off <<= 1) {
        const u32 v = (t >= off) ? ts[t - off] : 0u;
        __syncthreads();
        ts[t] += v;
        __syncthreads();
    }
    const u32 base = ts[t] - T;
    hist[4 * t]     = base;
    hist[4 * t + 1] = base + h0;
    hist[4 * t + 2] = base + h0 + h1;
    hist[4 * t + 3] = base + h0 + h1 + h2;

    #pragma unroll
    for (int j = 0; j < 4; ++j)
        asum[b * NCELLS + t + 1024 * j] = as_[t + 1024 * j];
    __syncthreads();

    #pragma unroll
    for (int j = 0; j < 16; ++j) {
        const int p  = t + 1024 * j;
        const int cl = cb_[p];
        const u32 pos = atomicAdd(&hist[cl], 1u);
        ecomb[b * NHW + pos] = ((u32)cl << 16) | (u32)p;
    }
}

// ============================================================================
// K3a (xatt variant): staging is a pure 16B-coalesced copy of the
// premultiplied bf16 plane. No atts read, no multiply, no convert.
// ============================================================================
__global__ __launch_bounds__(256) void k_gather_x(
    const u16* __restrict__ xatt, const u32* __restrict__ ecomb,
    const float* __restrict__ asum, float* __restrict__ out)
{
    __shared__ u16   xpl[NHW];     // 32 KB (bf16 x*att)
    __shared__ float acc[NCELLS];  // 16 KB

    const int t   = threadIdx.x;
    const int blk = blockIdx.x;
    const int b   = blk >> 8;
    const int c   = blk & 255;

    const uint4* src4 = reinterpret_cast<const uint4*>(xatt + (size_t)(b * NC + c) * NHW);
    uint4*       xpl4 = reinterpret_cast<uint4*>(xpl);
    float4*      acc4 = reinterpret_cast<float4*>(acc);

    uint4 st[8];
    #pragma unroll
    for (int k = 0; k < 8; ++k) st[k] = src4[t + 256 * k];

    const float4 z4 = make_float4(0.f, 0.f, 0.f, 0.f);
    #pragma unroll
    for (int k = 0; k < 4; ++k) acc4[t + 256 * k] = z4;
    #pragma unroll
    for (int k = 0; k < 8; ++k) xpl4[t + 256 * k] = st[k];
    __syncthreads();

    gather_accum(xpl, acc, ecomb + b * NHW + t * 64);
    __syncthreads();

    const float4* as4 = reinterpret_cast<const float4*>(asum + b * NCELLS);
    float4* ob4 = reinterpret_cast<float4*>(out + (size_t)(b * NC + c) * NCELLS);
    #pragma unroll
    for (int k = 0; k < 4; ++k) {
        float4 a = acc4[t + 256 * k];
        const float4 sv = as4[t + 256 * k];
        a.x /= (sv.x + EPSF);
        a.y /= (sv.y + EPSF);
        a.z /= (sv.z + EPSF);
        a.w /= (sv.w + EPSF);
        ob4[t + 256 * k] = a;
    }
}

// K3b (fallback): round-4 staging (x*atts -> bf16) + 4-stream ILP inner loop.
__global__ __launch_bounds__(256) void k_gather_nx(
    const float* __restrict__ x, const float* __restrict__ atts,
    const u32* __restrict__ ecomb, const float* __restrict__ asum,
    float* __restrict__ out)
{
    __shared__ u16   xpl[NHW];
    __shared__ float acc[NCELLS];

    const int t   = threadIdx.x;
    const int blk = blockIdx.x;
    const int b   = blk >> 8;
    const int c   = blk & 255;

    const float4* xp4  = reinterpret_cast<const float4*>(x + (size_t)(b * NC + c) * NHW);
    const float4* at4  = reinterpret_cast<const float4*>(atts + b * NHW);
    float4*       acc4 = reinterpret_cast<float4*>(acc);

    #pragma unroll
    for (int k = 0; k < 16; ++k) {
        const int idx = t + 256 * k;
        const float4 xv = xp4[idx];
        const float4 av = at4[idx];
        const u32 lo = (u32)f32_to_bf16_rn(xv.x * av.x)
                     | ((u32)f32_to_bf16_rn(xv.y * av.y) << 16);
        const u32 hi = (u32)f32_to_bf16_rn(xv.z * av.z)
                     | ((u32)f32_to_bf16_rn(xv.w * av.w) << 16);
        *reinterpret_cast<uint2*>(&xpl[idx * 4]) = make_uint2(lo, hi);
    }
    const float4 z4 = make_float4(0.f, 0.f, 0.f, 0.f);
    #pragma unroll
    for (int k = 0; k < 4; ++k) acc4[t + 256 * k] = z4;
    __syncthreads();

    gather_accum(xpl, acc, ecomb + b * NHW + t * 64);
    __syncthreads();

    const float4* as4 = reinterpret_cast<const float4*>(asum + b * NCELLS);
    float4* ob4 = reinterpret_cast<float4*>(out + (size_t)(b * NC + c) * NCELLS);
    #pragma unroll
    for (int k = 0; k < 4; ++k) {
        float4 a = acc4[t + 256 * k];
        const float4 sv = as4[t + 256 * k];
        a.x /= (sv.x + EPSF);
        a.y /= (sv.y + EPSF);
        a.z /= (sv.z + EPSF);
        a.w /= (sv.w + EPSF);
        ob4[t + 256 * k] = a;
    }
}

extern "C" void kernel_launch(void* const* d_in, const int* in_sizes, int n_in,
                              void* d_out, int out_size, void* d_ws, size_t ws_size,
                              hipStream_t stream)
{
    (void)in_sizes; (void)n_in; (void)out_size;
    const float* x  = (const float*)d_in[0];
    const float* cw = (const float*)d_in[1];
    const float* cb = (const float*)d_in[2];
    float* out = (float*)d_out;
    char*  ws  = (char*)d_ws;

    u16*   cells = (u16*)  (ws + WS_CELLS);
    float* atts  = (float*)(ws + WS_ATTS);
    u32*   ecomb = (u32*)  (ws + WS_ECOMB);
    float* asum  = (float*)(ws + WS_ASUM);

    if (ws_size >= WS_XATT_NEED) {
        u16* xatt = (u16*)(ws + WS_XATT);
        k_conv_x  <<<dim3(NB * 256), dim3(256),  0, stream>>>(x, cw, cb, out, cells, atts, xatt);
        k_sort    <<<dim3(NB),       dim3(1024), 0, stream>>>(cells, atts, ecomb, asum);
        k_gather_x<<<dim3(NB * NC),  dim3(256),  0, stream>>>(xatt, ecomb, asum, out);
    } else {
        k_conv_nx  <<<dim3(NB * 256), dim3(256),  0, stream>>>(x, cw, cb, out, cells, atts);
        k_sort     <<<dim3(NB),       dim3(1024), 0, stream>>>(cells, atts, ecomb, asum);
        k_gather_nx<<<dim3(NB * NC),  dim3(256),  0, stream>>>(x, atts, ecomb, asum, out);
    }
}